// Round 5
// baseline (175.087 us; speedup 1.0000x reference)
//
#include <hip/hip_runtime.h>
#include <math.h>

#define N_NODES 8192
#define LR_C 0.01f
#define EPS_C 1e-6f
#define NJ 32                      // j-chunks in repulsion
#define HASH_SLOTS (1u << 20)      // 4 MiB table, load factor 0.25
#define HEMPTY 0xFFFFFFFFu

// clear-region sizes in 16B vectors
#define HASH_V 262144              // 1M uints   = 4 MiB
#define X1_V   6144                // 24576 floats (8192*3)
#define LACC_V 6144                // 24576 floats (8192*3)
#define DEG_V  2048                // 8192 ints
#define TOT_V  (HASH_V + X1_V + LACC_V + DEG_V)   // 276480 = 1080*256

// ---------------- K0: init hash(0xFF) + x1 = positions + lacc/deg = 0 --------
__global__ __launch_bounds__(256) void init_clear(const float4* __restrict__ pos4,
                                                  float4* __restrict__ x1_4,
                                                  uint4* __restrict__ hash4,
                                                  float4* __restrict__ lacc4,
                                                  uint4* __restrict__ deg4) {
    int gid = blockIdx.x * blockDim.x + threadIdx.x;
    if (gid < HASH_V) {
        hash4[gid] = make_uint4(HEMPTY, HEMPTY, HEMPTY, HEMPTY);
    } else if (gid < HASH_V + X1_V) {
        int t = gid - HASH_V;
        x1_4[t] = pos4[t];
    } else if (gid < HASH_V + X1_V + LACC_V) {
        int t = gid - (HASH_V + X1_V);
        lacc4[t] = make_float4(0.f, 0.f, 0.f, 0.f);
    } else if (gid < TOT_V) {
        int t = gid - (HASH_V + X1_V + LACC_V);
        deg4[t] = make_uint4(0u, 0u, 0u, 0u);
    }
}

// ---------------- K1: fused constraint-scatter + edge-dedup(hash)+degree ------
// blocks [0,nbK): K constraint pairs; blocks [nbK, nbK+nbE): E edges
__global__ __launch_bounds__(256) void scatter_hash(
        const float* __restrict__ x0, const int* __restrict__ dist_idx,
        const float* __restrict__ dist_target, const int* __restrict__ edge_index,
        float* __restrict__ x1, unsigned int* __restrict__ hash,
        unsigned char* __restrict__ flags, int* __restrict__ deg,
        int K, int E, int nbK) {
    int blk = blockIdx.x;
    if (blk < nbK) {
        int k = blk * 256 + threadIdx.x;
        if (k >= K) return;
        int i = dist_idx[2 * k], j = dist_idx[2 * k + 1];
        float ax = x0[3 * i], ay = x0[3 * i + 1], az = x0[3 * i + 2];
        float bx = x0[3 * j], by = x0[3 * j + 1], bz = x0[3 * j + 2];
        float vx = ax - bx, vy = ay - by, vz = az - bz;
        float dist = sqrtf(vx * vx + vy * vy + vz * vz + 1e-12f);
        bool valid = (dist > EPS_C) && (i != j);
        float coef = valid ? (LR_C * 0.5f) * (dist - dist_target[k]) / dist : 0.0f;
        if (coef != 0.0f) {
            float cx = coef * vx, cy = coef * vy, cz = coef * vz;
            atomicAdd(&x1[3 * i],     -cx);
            atomicAdd(&x1[3 * i + 1], -cy);
            atomicAdd(&x1[3 * i + 2], -cz);
            atomicAdd(&x1[3 * j],      cx);
            atomicAdd(&x1[3 * j + 1],  cy);
            atomicAdd(&x1[3 * j + 2],  cz);
        }
    } else {
        int k = (blk - nbK) * 256 + threadIdx.x;
        if (k >= E) return;
        int a = edge_index[k];
        int b = edge_index[E + k];
        a = min(max(a, 0), N_NODES - 1);
        b = min(max(b, 0), N_NODES - 1);
        unsigned int key = ((unsigned)a << 13) | (unsigned)b;   // 26 bits, != HEMPTY
        unsigned int h = (key * 2654435761u) >> 12;             // top 20 bits
        bool unique = false;
        while (true) {
            unsigned int old = atomicCAS(&hash[h], HEMPTY, key);
            if (old == HEMPTY) { unique = true; break; }        // we inserted it
            if (old == key)   { break; }                        // duplicate
            h = (h + 1) & (HASH_SLOTS - 1);
        }
        flags[k] = unique ? 1 : 0;
        if (unique) {
            atomicAdd(&deg[a], 1);
            atomicAdd(&deg[b], 1);
        }
    }
}

// ---------------- K2: pairwise repulsion partials ----------------
// grid = (32 i-chunks, 32 j-chunks), block = 256
__global__ __launch_bounds__(256) void repulsion_partial(
        const float* __restrict__ x1, const float* __restrict__ min_dist,
        float4* __restrict__ partials) {
    __shared__ float4 pj[256];
    int t = threadIdx.x;
    int jbase = blockIdx.y * 256;
    int i = blockIdx.x * 256 + t;
    {
        int j = jbase + t;
        float a = x1[3 * j], b = x1[3 * j + 1], c = x1[3 * j + 2];
        pj[t] = make_float4(a, b, c, a * a + b * b + c * c);
    }
    __syncthreads();
    float xi = x1[3 * i], yi = x1[3 * i + 1], zi = x1[3 * i + 2];
    float sqi = xi * xi + yi * yi + zi * zi;
    float md = min_dist[0];
    const float c0 = 0.5f * LR_C;          // 0.005
    float c1 = c0 * md;
    float S = 0.f, axc = 0.f, ayc = 0.f, azc = 0.f;
    if (blockIdx.x == blockIdx.y) {
        int di = t;                         // self-pair position in tile
        #pragma unroll 4
        for (int jj = 0; jj < 256; ++jj) {
            float4 p = pj[jj];
            float dot = fmaf(xi, p.x, fmaf(yi, p.y, zi * p.z));
            float d2 = fmaf(-2.0f, dot, sqi + p.w);
            float r = __builtin_amdgcn_rsqf(fmaxf(d2, 1e-12f));
            float w = fmaxf(fmaf(c1, r, -c0), 0.0f);      // >0 iff d < md
            w = (d2 > 1e-12f && jj != di) ? w : 0.0f;
            S += w;
            axc = fmaf(w, p.x, axc);
            ayc = fmaf(w, p.y, ayc);
            azc = fmaf(w, p.z, azc);
        }
    } else {
        #pragma unroll 4
        for (int jj = 0; jj < 256; ++jj) {
            float4 p = pj[jj];
            float dot = fmaf(xi, p.x, fmaf(yi, p.y, zi * p.z));
            float d2 = fmaf(-2.0f, dot, sqi + p.w);
            float r = __builtin_amdgcn_rsqf(fmaxf(d2, 1e-12f));
            float w = fmaxf(fmaf(c1, r, -c0), 0.0f);
            w = (d2 > 1e-12f) ? w : 0.0f;
            S += w;
            axc = fmaf(w, p.x, axc);
            ayc = fmaf(w, p.y, ayc);
            azc = fmaf(w, p.z, azc);
        }
    }
    partials[blockIdx.y * N_NODES + i] = make_float4(axc, ayc, azc, S);
}

// ---------------- K3: finalize x2 + dinv + z (thread per row) ----------------
__global__ __launch_bounds__(256) void finalize(
        const float* __restrict__ x1, const float4* __restrict__ partials,
        const int* __restrict__ deg,
        float* __restrict__ x2, float* __restrict__ out_x,
        float* __restrict__ dinv, float4* __restrict__ z4) {
    int i = blockIdx.x * blockDim.x + threadIdx.x;
    if (i >= N_NODES) return;
    float S = 0.f, axc = 0.f, ayc = 0.f, azc = 0.f;
    #pragma unroll
    for (int c = 0; c < NJ; ++c) {
        float4 p = partials[c * N_NODES + i];
        axc += p.x; ayc += p.y; azc += p.z; S += p.w;
    }
    float xi = x1[3 * i], yi = x1[3 * i + 1], zi = x1[3 * i + 2];
    float ox = xi + xi * S - axc;
    float oy = yi + yi * S - ayc;
    float oz = zi + zi * S - azc;
    x2[3 * i] = ox; x2[3 * i + 1] = oy; x2[3 * i + 2] = oz;
    out_x[3 * i] = ox; out_x[3 * i + 1] = oy; out_x[3 * i + 2] = oz;
    int d = deg[i];
    float dv = (d == 0) ? 0.0f : 1.0f / sqrtf((float)d + EPS_C);
    dinv[i] = dv;
    z4[i] = make_float4(dv * ox, dv * oy, dv * oz, dv);
}

// ---------------- K4: Laplacian scatter over unique edges ----------------
// adj = setA + setA^T: each unique directed edge (a,b) adds z_b to row a
// and z_a to row b (self-loops contribute twice, matching weight 2).
__global__ __launch_bounds__(256) void lap_scatter(
        const int* __restrict__ edge_index, const unsigned char* __restrict__ flags,
        const float4* __restrict__ z4, float* __restrict__ lacc, int E) {
    int k = blockIdx.x * blockDim.x + threadIdx.x;
    if (k >= E) return;
    if (!flags[k]) return;
    int a = edge_index[k];
    int b = edge_index[E + k];
    a = min(max(a, 0), N_NODES - 1);
    b = min(max(b, 0), N_NODES - 1);
    float4 zb = z4[b];
    float4 za = z4[a];
    atomicAdd(&lacc[3 * a],     zb.x);
    atomicAdd(&lacc[3 * a + 1], zb.y);
    atomicAdd(&lacc[3 * a + 2], zb.z);
    atomicAdd(&lacc[3 * b],     za.x);
    atomicAdd(&lacc[3 * b + 1], za.y);
    atomicAdd(&lacc[3 * b + 2], za.z);
}

// ---------------- K5: curvature ----------------
__global__ __launch_bounds__(256) void curvature(
        const float* __restrict__ x2, const float* __restrict__ dinv,
        const float* __restrict__ lacc, float* __restrict__ out_curv) {
    int i = blockIdx.x * blockDim.x + threadIdx.x;
    if (i >= N_NODES) return;
    float dv = dinv[i];
    float lx = x2[3 * i]     - dv * lacc[3 * i];
    float ly = x2[3 * i + 1] - dv * lacc[3 * i + 1];
    float lz = x2[3 * i + 2] - dv * lacc[3 * i + 2];
    out_curv[i] = sqrtf(lx * lx + ly * ly + lz * lz + 1e-12f);
}

extern "C" void kernel_launch(void* const* d_in, const int* in_sizes, int n_in,
                              void* d_out, int out_size, void* d_ws, size_t ws_size,
                              hipStream_t stream) {
    const float* positions   = (const float*)d_in[0];
    const int*   edge_index  = (const int*)d_in[1];
    const int*   dist_idx    = (const int*)d_in[2];
    const float* dist_target = (const float*)d_in[3];
    const float* min_dist    = (const float*)d_in[4];
    float* out = (float*)d_out;

    const int E = in_sizes[1] / 2;   // 262144
    const int K = in_sizes[2] / 2;   // 65536

    // workspace layout (16B aligned)
    char* ws = (char*)d_ws;
    const size_t X1_OFF   = 0;                                          //  96 KiB
    const size_t X2_OFF   = X1_OFF + (size_t)N_NODES * 3 * 4;           //  96 KiB
    const size_t Z4_OFF   = X2_OFF + (size_t)N_NODES * 3 * 4;           // 128 KiB
    const size_t DINV_OFF = Z4_OFF + (size_t)N_NODES * 16;              //  32 KiB
    const size_t DEG_OFF  = DINV_OFF + (size_t)N_NODES * 4;             //  32 KiB
    const size_t LACC_OFF = DEG_OFF + (size_t)N_NODES * 4;              //  96 KiB
    const size_t FLAG_OFF = LACC_OFF + (size_t)N_NODES * 3 * 4;         // 256 KiB
    const size_t PART_OFF = FLAG_OFF + (size_t)E;                       //   4 MiB
    const size_t HASH_OFF = PART_OFF + (size_t)NJ * N_NODES * 16;       //   4 MiB

    float* x1            = (float*)(ws + X1_OFF);
    float* x2            = (float*)(ws + X2_OFF);
    float4* z4           = (float4*)(ws + Z4_OFF);
    float* dinv          = (float*)(ws + DINV_OFF);
    int*   deg           = (int*)(ws + DEG_OFF);
    float* lacc          = (float*)(ws + LACC_OFF);
    unsigned char* flags = (unsigned char*)(ws + FLAG_OFF);
    float4* partials     = (float4*)(ws + PART_OFF);
    unsigned int* hash   = (unsigned int*)(ws + HASH_OFF);

    init_clear<<<TOT_V / 256, 256, 0, stream>>>(
        (const float4*)positions, (float4*)x1, (uint4*)hash,
        (float4*)lacc, (uint4*)deg);

    int nbK = (K + 255) / 256;           // 256
    int nbE = (E + 255) / 256;           // 1024
    scatter_hash<<<nbK + nbE, 256, 0, stream>>>(
        positions, dist_idx, dist_target, edge_index,
        x1, hash, flags, deg, K, E, nbK);

    dim3 grid_rep(N_NODES / 256, NJ);
    repulsion_partial<<<grid_rep, 256, 0, stream>>>(x1, min_dist, partials);

    finalize<<<N_NODES / 256, 256, 0, stream>>>(x1, partials, deg,
                                                x2, out, dinv, z4);

    lap_scatter<<<nbE, 256, 0, stream>>>(edge_index, flags, z4, lacc, E);

    curvature<<<N_NODES / 256, 256, 0, stream>>>(x2, dinv, lacc,
                                                 out + 3 * N_NODES);
}

// Round 6
// 128.243 us; speedup vs baseline: 1.3653x; 1.3653x over previous
//
#include <hip/hip_runtime.h>
#include <math.h>

#define N_NODES 8192
#define N3      24576              // N_NODES * 3
#define LR_C 0.01f
#define EPS_C 1e-6f
#define NJ 32                      // j-chunks in repulsion
#define HASH_SLOTS (1u << 20)      // 4 MiB table
#define HEMPTY 0xFFFFFFFFu
#define NB_SC 64                   // constraint-scatter blocks
#define NB_DG 64                   // degree-histogram blocks
#define NB_LP 64                   // laplacian-histogram blocks

// ---------------- K0: clear hash (4 MiB) ----------------
// grid 1024 x 256 = 262144 threads, one uint4 each.
__global__ __launch_bounds__(256) void init_hash(uint4* __restrict__ hash4) {
    int gid = blockIdx.x * blockDim.x + threadIdx.x;
    hash4[gid] = make_uint4(HEMPTY, HEMPTY, HEMPTY, HEMPTY);
}

// ---------------- K1: constraint scatter into LDS partials ----------------
// 64 blocks x 512. Each block: full 24576-float corr array in LDS.
__global__ __launch_bounds__(512) void scatter_corr(
        const float* __restrict__ x0, const int* __restrict__ dist_idx,
        const float* __restrict__ dist_target,
        float* __restrict__ corr_part, int K) {
    __shared__ float corr[N3];                      // 96 KiB
    for (int t = threadIdx.x; t < N3; t += 512) corr[t] = 0.f;
    __syncthreads();
    int per = (K + NB_SC - 1) / NB_SC;              // 1024
    int base = blockIdx.x * per;
    for (int kk = threadIdx.x; kk < per; kk += 512) {
        int k = base + kk;
        if (k >= K) break;
        int i = dist_idx[2 * k], j = dist_idx[2 * k + 1];
        float ax = x0[3 * i], ay = x0[3 * i + 1], az = x0[3 * i + 2];
        float bx = x0[3 * j], by = x0[3 * j + 1], bz = x0[3 * j + 2];
        float vx = ax - bx, vy = ay - by, vz = az - bz;
        float dist = sqrtf(vx * vx + vy * vy + vz * vz + 1e-12f);
        bool valid = (dist > EPS_C) && (i != j);
        float coef = valid ? (LR_C * 0.5f) * (dist - dist_target[k]) / dist : 0.0f;
        if (coef != 0.0f) {
            float cx = coef * vx, cy = coef * vy, cz = coef * vz;
            atomicAdd(&corr[3 * i],     -cx);
            atomicAdd(&corr[3 * i + 1], -cy);
            atomicAdd(&corr[3 * i + 2], -cz);
            atomicAdd(&corr[3 * j],      cx);
            atomicAdd(&corr[3 * j + 1],  cy);
            atomicAdd(&corr[3 * j + 2],  cz);
        }
    }
    __syncthreads();
    float* dst = corr_part + (size_t)blockIdx.x * N3;
    for (int t = threadIdx.x; t < N3; t += 512) dst[t] = corr[t];
}

// ---------------- K2: x1 = positions + sum of corr partials ----------------
// 96 blocks x 256 = 24576 threads.
__global__ __launch_bounds__(256) void x1_reduce(
        const float* __restrict__ pos, const float* __restrict__ corr_part,
        float* __restrict__ x1) {
    int t = blockIdx.x * blockDim.x + threadIdx.x;
    if (t >= N3) return;
    float s = pos[t];
    #pragma unroll 8
    for (int p = 0; p < NB_SC; ++p) s += corr_part[(size_t)p * N3 + t];
    x1[t] = s;
}

// ---------------- K3: edge dedup via hash CAS -> flags ----------------
// 1024 blocks x 256 = one thread per edge.
__global__ __launch_bounds__(256) void hash_flags(
        const int* __restrict__ edge_index, unsigned int* __restrict__ hash,
        unsigned char* __restrict__ flags, int E) {
    int k = blockIdx.x * blockDim.x + threadIdx.x;
    if (k >= E) return;
    int a = edge_index[k];
    int b = edge_index[E + k];
    a = min(max(a, 0), N_NODES - 1);
    b = min(max(b, 0), N_NODES - 1);
    unsigned int key = ((unsigned)a << 13) | (unsigned)b;   // 26 bits != HEMPTY
    unsigned int h = (key * 2654435761u) >> 12;             // [0, 2^20)
    bool unique = false;
    while (true) {
        unsigned int old = atomicCAS(&hash[h], HEMPTY, key);
        if (old == HEMPTY) { unique = true; break; }
        if (old == key)   { break; }
        h = (h + 1) & (HASH_SLOTS - 1);
    }
    flags[k] = unique ? 1 : 0;
}

// ---------------- K4: degree LDS histogram partials ----------------
// 64 blocks x 512; full 8192-int histogram per block.
__global__ __launch_bounds__(512) void deg_hist(
        const int* __restrict__ edge_index, const unsigned char* __restrict__ flags,
        int* __restrict__ deg_part, int E) {
    __shared__ int hist[N_NODES];                   // 32 KiB
    for (int t = threadIdx.x; t < N_NODES; t += 512) hist[t] = 0;
    __syncthreads();
    int per = (E + NB_DG - 1) / NB_DG;              // 4096
    int base = blockIdx.x * per;
    for (int kk = threadIdx.x; kk < per; kk += 512) {
        int k = base + kk;
        if (k >= E) break;
        if (!flags[k]) continue;
        int a = edge_index[k];
        int b = edge_index[E + k];
        a = min(max(a, 0), N_NODES - 1);
        b = min(max(b, 0), N_NODES - 1);
        atomicAdd(&hist[a], 1);
        atomicAdd(&hist[b], 1);
    }
    __syncthreads();
    int* dst = deg_part + (size_t)blockIdx.x * N_NODES;
    for (int t = threadIdx.x; t < N_NODES; t += 512) dst[t] = hist[t];
}

// ---------------- K5: pairwise repulsion partials ----------------
// grid = (32 i-chunks, 32 j-chunks), block = 256
__global__ __launch_bounds__(256) void repulsion_partial(
        const float* __restrict__ x1, const float* __restrict__ min_dist,
        float4* __restrict__ partials) {
    __shared__ float4 pj[256];
    int t = threadIdx.x;
    int jbase = blockIdx.y * 256;
    int i = blockIdx.x * 256 + t;
    {
        int j = jbase + t;
        float a = x1[3 * j], b = x1[3 * j + 1], c = x1[3 * j + 2];
        pj[t] = make_float4(a, b, c, a * a + b * b + c * c);
    }
    __syncthreads();
    float xi = x1[3 * i], yi = x1[3 * i + 1], zi = x1[3 * i + 2];
    float sqi = xi * xi + yi * yi + zi * zi;
    float md = min_dist[0];
    const float c0 = 0.5f * LR_C;          // 0.005
    float c1 = c0 * md;
    float S = 0.f, axc = 0.f, ayc = 0.f, azc = 0.f;
    if (blockIdx.x == blockIdx.y) {
        int di = t;                         // self-pair position in tile
        #pragma unroll 4
        for (int jj = 0; jj < 256; ++jj) {
            float4 p = pj[jj];
            float dot = fmaf(xi, p.x, fmaf(yi, p.y, zi * p.z));
            float d2 = fmaf(-2.0f, dot, sqi + p.w);
            float r = __builtin_amdgcn_rsqf(fmaxf(d2, 1e-12f));
            float w = fmaxf(fmaf(c1, r, -c0), 0.0f);      // >0 iff d < md
            w = (d2 > 1e-12f && jj != di) ? w : 0.0f;
            S += w;
            axc = fmaf(w, p.x, axc);
            ayc = fmaf(w, p.y, ayc);
            azc = fmaf(w, p.z, azc);
        }
    } else {
        #pragma unroll 4
        for (int jj = 0; jj < 256; ++jj) {
            float4 p = pj[jj];
            float dot = fmaf(xi, p.x, fmaf(yi, p.y, zi * p.z));
            float d2 = fmaf(-2.0f, dot, sqi + p.w);
            float r = __builtin_amdgcn_rsqf(fmaxf(d2, 1e-12f));
            float w = fmaxf(fmaf(c1, r, -c0), 0.0f);
            w = (d2 > 1e-12f) ? w : 0.0f;
            S += w;
            axc = fmaf(w, p.x, axc);
            ayc = fmaf(w, p.y, ayc);
            azc = fmaf(w, p.z, azc);
        }
    }
    partials[blockIdx.y * N_NODES + i] = make_float4(axc, ayc, azc, S);
}

// ---------------- K6: finalize x2 + dinv + z (thread per row) ----------------
__global__ __launch_bounds__(256) void finalize(
        const float* __restrict__ x1, const float4* __restrict__ partials,
        const int* __restrict__ deg_part,
        float* __restrict__ x2, float* __restrict__ out_x,
        float* __restrict__ dinv, float4* __restrict__ z4) {
    int i = blockIdx.x * blockDim.x + threadIdx.x;
    if (i >= N_NODES) return;
    float S = 0.f, axc = 0.f, ayc = 0.f, azc = 0.f;
    #pragma unroll
    for (int c = 0; c < NJ; ++c) {
        float4 p = partials[(size_t)c * N_NODES + i];
        axc += p.x; ayc += p.y; azc += p.z; S += p.w;
    }
    int d = 0;
    #pragma unroll 8
    for (int p = 0; p < NB_DG; ++p) d += deg_part[(size_t)p * N_NODES + i];
    float xi = x1[3 * i], yi = x1[3 * i + 1], zi = x1[3 * i + 2];
    float ox = xi + xi * S - axc;
    float oy = yi + yi * S - ayc;
    float oz = zi + zi * S - azc;
    x2[3 * i] = ox; x2[3 * i + 1] = oy; x2[3 * i + 2] = oz;
    out_x[3 * i] = ox; out_x[3 * i + 1] = oy; out_x[3 * i + 2] = oz;
    float dv = (d == 0) ? 0.0f : 1.0f / sqrtf((float)d + EPS_C);
    dinv[i] = dv;
    z4[i] = make_float4(dv * ox, dv * oy, dv * oz, dv);
}

// ---------------- K7: Laplacian LDS accumulation partials ----------------
// 64 blocks x 512; full 24576-float accumulator per block.
// Each unique directed edge (a,b): acc[a] += z_b, acc[b] += z_a.
__global__ __launch_bounds__(512) void lap_hist(
        const int* __restrict__ edge_index, const unsigned char* __restrict__ flags,
        const float4* __restrict__ z4, float* __restrict__ lap_part, int E) {
    __shared__ float acc[N3];                       // 96 KiB
    for (int t = threadIdx.x; t < N3; t += 512) acc[t] = 0.f;
    __syncthreads();
    int per = (E + NB_LP - 1) / NB_LP;              // 4096
    int base = blockIdx.x * per;
    for (int kk = threadIdx.x; kk < per; kk += 512) {
        int k = base + kk;
        if (k >= E) break;
        if (!flags[k]) continue;
        int a = edge_index[k];
        int b = edge_index[E + k];
        a = min(max(a, 0), N_NODES - 1);
        b = min(max(b, 0), N_NODES - 1);
        float4 zb = z4[b];
        float4 za = z4[a];
        atomicAdd(&acc[3 * a],     zb.x);
        atomicAdd(&acc[3 * a + 1], zb.y);
        atomicAdd(&acc[3 * a + 2], zb.z);
        atomicAdd(&acc[3 * b],     za.x);
        atomicAdd(&acc[3 * b + 1], za.y);
        atomicAdd(&acc[3 * b + 2], za.z);
    }
    __syncthreads();
    float* dst = lap_part + (size_t)blockIdx.x * N3;
    for (int t = threadIdx.x; t < N3; t += 512) dst[t] = acc[t];
}

// ---------------- K8: curvature (reduce lap partials) ----------------
__global__ __launch_bounds__(256) void curvature(
        const float* __restrict__ x2, const float* __restrict__ dinv,
        const float* __restrict__ lap_part, float* __restrict__ out_curv) {
    int i = blockIdx.x * blockDim.x + threadIdx.x;
    if (i >= N_NODES) return;
    float lx = 0.f, ly = 0.f, lz = 0.f;
    #pragma unroll 8
    for (int p = 0; p < NB_LP; ++p) {
        const float* src = lap_part + (size_t)p * N3 + 3 * i;
        lx += src[0]; ly += src[1]; lz += src[2];
    }
    float dv = dinv[i];
    float Lx = x2[3 * i]     - dv * lx;
    float Ly = x2[3 * i + 1] - dv * ly;
    float Lz = x2[3 * i + 2] - dv * lz;
    out_curv[i] = sqrtf(Lx * Lx + Ly * Ly + Lz * Lz + 1e-12f);
}

extern "C" void kernel_launch(void* const* d_in, const int* in_sizes, int n_in,
                              void* d_out, int out_size, void* d_ws, size_t ws_size,
                              hipStream_t stream) {
    const float* positions   = (const float*)d_in[0];
    const int*   edge_index  = (const int*)d_in[1];
    const int*   dist_idx    = (const int*)d_in[2];
    const float* dist_target = (const float*)d_in[3];
    const float* min_dist    = (const float*)d_in[4];
    float* out = (float*)d_out;

    const int E = in_sizes[1] / 2;   // 262144
    const int K = in_sizes[2] / 2;   // 65536

    // ---- workspace layout (16B aligned), with lifetime overlays ----
    // persistent: x1, x2, z4, dinv, flags
    // region R1 (6 MiB): corr_part (K1->K2), then repulsion partials (K5->K6)
    // region R2 (6 MiB): hash 4MiB (K0->K3) + deg_part 2MiB (K4->K6),
    //                    then lap_part 6MiB (K7->K8)
    char* ws = (char*)d_ws;
    const size_t X1_OFF   = 0;                                   //  96 KiB
    const size_t X2_OFF   = X1_OFF   + (size_t)N3 * 4;           //  96 KiB
    const size_t Z4_OFF   = X2_OFF   + (size_t)N3 * 4;           // 128 KiB
    const size_t DINV_OFF = Z4_OFF   + (size_t)N_NODES * 16;     //  32 KiB
    const size_t FLAG_OFF = DINV_OFF + (size_t)N_NODES * 4;      // 256 KiB
    const size_t R1_OFF   = FLAG_OFF + (size_t)E;                //   6 MiB
    const size_t R2_OFF   = R1_OFF   + (size_t)NB_SC * N3 * 4;   //   6 MiB

    float* x1            = (float*)(ws + X1_OFF);
    float* x2            = (float*)(ws + X2_OFF);
    float4* z4           = (float4*)(ws + Z4_OFF);
    float* dinv          = (float*)(ws + DINV_OFF);
    unsigned char* flags = (unsigned char*)(ws + FLAG_OFF);
    float* corr_part     = (float*)(ws + R1_OFF);
    float4* rep_part     = (float4*)(ws + R1_OFF);               // overlay
    unsigned int* hash   = (unsigned int*)(ws + R2_OFF);
    int* deg_part        = (int*)(ws + R2_OFF + (size_t)HASH_SLOTS * 4);
    float* lap_part      = (float*)(ws + R2_OFF);                // overlay

    // K0: clear hash. 1M uints = 262144 uint4.
    init_hash<<<1024, 256, 0, stream>>>((uint4*)hash);

    // K1: constraint corrections -> LDS partials
    scatter_corr<<<NB_SC, 512, 0, stream>>>(positions, dist_idx, dist_target,
                                            corr_part, K);

    // K2: x1 = positions + sum(partials)
    x1_reduce<<<(N3 + 255) / 256, 256, 0, stream>>>(positions, corr_part, x1);

    // K3: dedup flags (only remaining device atomics)
    hash_flags<<<(E + 255) / 256, 256, 0, stream>>>(edge_index, hash, flags, E);

    // K4: degree histogram partials
    deg_hist<<<NB_DG, 512, 0, stream>>>(edge_index, flags, deg_part, E);

    // K5: N^2 repulsion partials (into R1 overlay; corr_part is dead)
    dim3 grid_rep(N_NODES / 256, NJ);
    repulsion_partial<<<grid_rep, 256, 0, stream>>>(x1, min_dist, rep_part);

    // K6: finalize x2/out_x/dinv/z4 (reads rep_part + deg_part)
    finalize<<<N_NODES / 256, 256, 0, stream>>>(x1, rep_part, deg_part,
                                                x2, out, dinv, z4);

    // K7: Laplacian LDS partials (into R2 overlay; hash & deg_part dead)
    lap_hist<<<NB_LP, 512, 0, stream>>>(edge_index, flags, z4, lap_part, E);

    // K8: curvature
    curvature<<<N_NODES / 256, 256, 0, stream>>>(x2, dinv, lap_part,
                                                 out + 3 * N_NODES);
}